// Round 4
// baseline (475.302 us; speedup 1.0000x reference)
//
#include <hip/hip_runtime.h>
#include <hip/hip_bf16.h>

#define NN 8192
#define DIM 128

typedef __attribute__((ext_vector_type(8))) short bf16x8;
typedef __attribute__((ext_vector_type(4))) float f32x4;
typedef __attribute__((ext_vector_type(4))) unsigned int u32x4;

static __device__ inline short f2bf(float x) {
    __hip_bfloat16 b = __float2bfloat16(x);
    return *reinterpret_cast<short*>(&b);
}

// ---------------------------------------------------------------------------
// K1: Wh = h @ W^T -> whbT (bf16, [DIM][NN] col-major for MFMA B-frags).
// Block 0 additionally computes w12 = {W^T a[:128], W^T a[128:]} (W is
// already staged in LDS there).
// ---------------------------------------------------------------------------
__global__ __launch_bounds__(256) void k1_wh(const float* __restrict__ h,
                                             const float* __restrict__ W,
                                             const float* __restrict__ a,
                                             __hip_bfloat16* __restrict__ whbT,
                                             float* __restrict__ w12) {
    __shared__ float WT[128][129];
    __shared__ float h_s[16][128];
    __shared__ float a_sh[256];
    __shared__ __hip_bfloat16 wt_s[128][16];

    const int tid = threadIdx.x;
    const int r0 = blockIdx.x * 16;

    for (int idx = tid; idx < 128 * 128; idx += 256) {
        int d = idx >> 7, k = idx & 127;
        WT[k][d] = W[idx];
    }
    for (int idx = tid; idx < 16 * 128; idx += 256)
        h_s[idx >> 7][idx & 127] = h[(size_t)(r0 + (idx >> 7)) * DIM + (idx & 127)];
    a_sh[tid] = a[tid];
    __syncthreads();

    const int d = tid & 127;
    const int g = tid >> 7;
    float acc[8] = {0, 0, 0, 0, 0, 0, 0, 0};
    for (int k = 0; k < 128; ++k) {
        float wv = WT[k][d];
        #pragma unroll
        for (int rr = 0; rr < 8; ++rr)
            acc[rr] += h_s[g * 8 + rr][k] * wv;
    }
    #pragma unroll
    for (int rr = 0; rr < 8; ++rr)
        wt_s[d][g * 8 + rr] = __float2bfloat16(acc[rr]);

    if (blockIdx.x == 0 && tid < 128) {      // fused k0 (conflict-free WT rows)
        float s1 = 0.f, s2 = 0.f;
        for (int o = 0; o < 128; ++o) {
            float wv = WT[tid][o];
            s1 += wv * a_sh[o];
            s2 += wv * a_sh[128 + o];
        }
        w12[tid] = s1;
        w12[128 + tid] = s2;
    }
    __syncthreads();
    for (int idx = tid; idx < 128 * 16; idx += 256) {
        int dd = idx >> 4, r = idx & 15;
        whbT[(size_t)dd * NN + r0 + r] = wt_s[dd][r];
    }
}

// ---------------------------------------------------------------------------
// K2a: per-row a1 = h.w1, a2 = h.w2, E1 = exp(a2), E2 = exp(0.2 a2)
// ---------------------------------------------------------------------------
__global__ __launch_bounds__(256) void k2a_rows(const float* __restrict__ h,
                                                const float* __restrict__ w12,
                                                float* __restrict__ a1g,
                                                float* __restrict__ a2g,
                                                float* __restrict__ E1g,
                                                float* __restrict__ E2g) {
    const int wid = threadIdx.x >> 6, lane = threadIdx.x & 63;
    const int i = blockIdx.x * 4 + wid;
    const float* hr = h + (size_t)i * DIM;
    float h0 = hr[lane], h1 = hr[lane + 64];
    float s1 = h0 * w12[lane] + h1 * w12[lane + 64];
    float s2 = h0 * w12[128 + lane] + h1 * w12[192 + lane];
    #pragma unroll
    for (int o = 32; o >= 1; o >>= 1) {
        s1 += __shfl_xor(s1, o, 64);
        s2 += __shfl_xor(s2, o, 64);
    }
    if (lane == 0) {
        a1g[i] = s1;
        a2g[i] = s2;
        E1g[i] = expf(s2);
        E2g[i] = expf(0.2f * s2);
    }
}

// ---------------------------------------------------------------------------
// SA: stream adj (1 wave per row): natural-order bitmask (bit j of word j>>5
// is col j) via stride-64 dword loads + ballot, plus row softmax sums.
// No max-shift needed (|a1+a2| small, exp safe); no-neighbor <=> s1+s2==0.
// ---------------------------------------------------------------------------
__global__ __launch_bounds__(256) void sa_scan(const int* __restrict__ adj,
                                               const float* __restrict__ a1g,
                                               const float* __restrict__ a2g,
                                               const float* __restrict__ E1g,
                                               const float* __restrict__ E2g,
                                               unsigned* __restrict__ bm,
                                               float* __restrict__ crow) {
    const int wid = threadIdx.x >> 6, lane = threadIdx.x & 63;
    const int i = blockIdx.x * 4 + wid;
    const float a1i = a1g[i];
    const int* arow = adj + (size_t)i * NN;
    unsigned* brow = bm + (size_t)i * (NN / 32);

    float s1 = 0.f, s2 = 0.f;
    for (int it = 0; it < NN / 256; ++it) {
        const int j0 = it * 256;
        int v0 = __builtin_nontemporal_load(arow + j0 + lane);
        int v1 = __builtin_nontemporal_load(arow + j0 + 64 + lane);
        int v2 = __builtin_nontemporal_load(arow + j0 + 128 + lane);
        int v3 = __builtin_nontemporal_load(arow + j0 + 192 + lane);
        unsigned long long m0 = __ballot(v0 != 0);
        unsigned long long m1 = __ballot(v1 != 0);
        unsigned long long m2 = __ballot(v2 != 0);
        unsigned long long m3 = __ballot(v3 != 0);
        if (lane == 0) {
            u32x4 w;
            w.x = (unsigned)m0; w.y = (unsigned)(m0 >> 32);
            w.z = (unsigned)m1; w.w = (unsigned)(m1 >> 32);
            *(u32x4*)(brow + it * 8) = w;
        } else if (lane == 32) {
            u32x4 w;
            w.x = (unsigned)m2; w.y = (unsigned)(m2 >> 32);
            w.z = (unsigned)m3; w.w = (unsigned)(m3 >> 32);
            *(u32x4*)(brow + it * 8 + 4) = w;
        }
        int j = j0 + lane;
        float x2 = a2g[j]; bool px = (a1i + x2 >= 0.f);
        s1 += (v0 && px) ? E1g[j] : 0.f;  s2 += (v0 && !px) ? E2g[j] : 0.f;
        j = j0 + 64 + lane;
        x2 = a2g[j]; px = (a1i + x2 >= 0.f);
        s1 += (v1 && px) ? E1g[j] : 0.f;  s2 += (v1 && !px) ? E2g[j] : 0.f;
        j = j0 + 128 + lane;
        x2 = a2g[j]; px = (a1i + x2 >= 0.f);
        s1 += (v2 && px) ? E1g[j] : 0.f;  s2 += (v2 && !px) ? E2g[j] : 0.f;
        j = j0 + 192 + lane;
        x2 = a2g[j]; px = (a1i + x2 >= 0.f);
        s1 += (v3 && px) ? E1g[j] : 0.f;  s2 += (v3 && !px) ? E2g[j] : 0.f;
    }
    #pragma unroll
    for (int o = 32; o >= 1; o >>= 1) {
        s1 += __shfl_xor(s1, o, 64);
        s2 += __shfl_xor(s2, o, 64);
    }
    if (lane == 0) {
        float c1 = 0.f, c2 = 0.f;
        if (s1 + s2 > 0.f) {
            float e1v = expf(a1i);
            float e2v = expf(0.2f * a1i);
            float S = e1v * s1 + e2v * s2;
            c1 = e1v / S;
            c2 = e2v / S;
        }
        crow[i * 4 + 0] = c1;
        crow[i * 4 + 1] = c2;
        crow[i * 4 + 2] = a1i;
        crow[i * 4 + 3] = 0.f;
    }
}

// ---------------------------------------------------------------------------
// SB: barrier-free fused alpha-write + PV MFMA.
// 512 blocks x 16 rows, 8 waves; wave wv owns k-slice [wv*1024, wv*1024+1024).
// Each lane computes its 8 alpha values directly in A-frag layout
// (row = lane&15, k = kk + (lane>>4)*8 + e), NT-stores them f32 to global,
// converts in-register to bf16 A-frag, MFMAs vs 8 B-frags from L2-hot whbT.
// No LDS / no syncthreads in the loop; one LDS reduction at the end.
// ---------------------------------------------------------------------------
__global__ __launch_bounds__(512, 4) void sb_pv(const unsigned* __restrict__ bm,
                                                const float* __restrict__ crowG,
                                                const float* __restrict__ a2g,
                                                const float* __restrict__ E1g,
                                                const float* __restrict__ E2g,
                                                const __hip_bfloat16* __restrict__ whbT,
                                                float* __restrict__ alpha,
                                                float* __restrict__ out) {
    __shared__ float red[8][16][132];        // 66 KB, pad 132: bank-safe + 16B aligned

    const int tid = threadIdx.x;
    const int wv = tid >> 6, lane = tid & 63;
    const int r0 = blockIdx.x * 16;
    const int row = r0 + (lane & 15);
    const int kb = wv * (NN / 8);            // 1024-wide k-slice per wave
    const int kq8 = (lane >> 4) * 8;

    f32x4 cw = *(const f32x4*)(crowG + row * 4);
    const float c1 = cw.x, c2 = cw.y, a1i = cw.z;

    const unsigned* bmrow = bm + (size_t)row * (NN / 32) + (kb >> 5);
    const float* a2p = a2g + kb + kq8;
    const float* e1p = E1g + kb + kq8;
    const float* e2p = E2g + kb + kq8;
    float* alr = alpha + (size_t)row * NN + kb + kq8;
    const short* wb = reinterpret_cast<const short*>(whbT);

    f32x4 acc[8];
    #pragma unroll
    for (int n = 0; n < 8; ++n) acc[n] = (f32x4){0.f, 0.f, 0.f, 0.f};

    for (int kk = 0; kk < NN / 8; kk += 32) {
        const unsigned byte = (bmrow[kk >> 5] >> kq8) & 0xffu;
        bf16x8 af;
        {
            f32x4 x2a = *(const f32x4*)(a2p + kk);
            f32x4 e1a = *(const f32x4*)(e1p + kk);
            f32x4 e2a = *(const f32x4*)(e2p + kk);
            f32x4 alo;
            alo.x = (byte & 1u) ? ((a1i + x2a.x >= 0.f) ? c1 * e1a.x : c2 * e2a.x) : 0.f;
            alo.y = (byte & 2u) ? ((a1i + x2a.y >= 0.f) ? c1 * e1a.y : c2 * e2a.y) : 0.f;
            alo.z = (byte & 4u) ? ((a1i + x2a.z >= 0.f) ? c1 * e1a.z : c2 * e2a.z) : 0.f;
            alo.w = (byte & 8u) ? ((a1i + x2a.w >= 0.f) ? c1 * e1a.w : c2 * e2a.w) : 0.f;
            __builtin_nontemporal_store(alo, (f32x4*)(alr + kk));
            af[0] = f2bf(alo.x); af[1] = f2bf(alo.y);
            af[2] = f2bf(alo.z); af[3] = f2bf(alo.w);
        }
        {
            f32x4 x2b = *(const f32x4*)(a2p + kk + 4);
            f32x4 e1b = *(const f32x4*)(e1p + kk + 4);
            f32x4 e2b = *(const f32x4*)(e2p + kk + 4);
            f32x4 ahi;
            ahi.x = (byte & 16u)  ? ((a1i + x2b.x >= 0.f) ? c1 * e1b.x : c2 * e2b.x) : 0.f;
            ahi.y = (byte & 32u)  ? ((a1i + x2b.y >= 0.f) ? c1 * e1b.y : c2 * e2b.y) : 0.f;
            ahi.z = (byte & 64u)  ? ((a1i + x2b.z >= 0.f) ? c1 * e1b.z : c2 * e2b.z) : 0.f;
            ahi.w = (byte & 128u) ? ((a1i + x2b.w >= 0.f) ? c1 * e1b.w : c2 * e2b.w) : 0.f;
            __builtin_nontemporal_store(ahi, (f32x4*)(alr + kk + 4));
            af[4] = f2bf(ahi.x); af[5] = f2bf(ahi.y);
            af[6] = f2bf(ahi.z); af[7] = f2bf(ahi.w);
        }
        #pragma unroll
        for (int n = 0; n < 8; ++n) {
            bf16x8 bf = *(const bf16x8*)(wb + (size_t)(n * 16 + (lane & 15)) * NN + kb + kk + kq8);
            acc[n] = __builtin_amdgcn_mfma_f32_16x16x32_bf16(af, bf, acc[n], 0, 0, 0);
        }
    }

    // stage per-wave partials, one barrier, reduce 8 k-slices -> out
    #pragma unroll
    for (int n = 0; n < 8; ++n) {
        #pragma unroll
        for (int q = 0; q < 4; ++q)
            red[wv][(lane >> 4) * 4 + q][n * 16 + (lane & 15)] = acc[n][q];
    }
    __syncthreads();
    const int idx = tid * 4;                 // 2048 outputs, 4 per thread
    const int r = idx >> 7, c = idx & 127;
    f32x4 s = (f32x4){0.f, 0.f, 0.f, 0.f};
    #pragma unroll
    for (int w = 0; w < 8; ++w) s += *(const f32x4*)(&red[w][r][c]);
    *(f32x4*)(out + (size_t)(r0 + r) * DIM + c) = s;
}

// ---------------------------------------------------------------------------
extern "C" void kernel_launch(void* const* d_in, const int* in_sizes, int n_in,
                              void* d_out, int out_size, void* d_ws, size_t ws_size,
                              hipStream_t stream) {
    const float* h   = (const float*)d_in[0];
    const int*   adj = (const int*)d_in[1];
    const float* W   = (const float*)d_in[2];
    const float* a   = (const float*)d_in[3];

    float* out   = (float*)d_out;
    float* alpha = out + (size_t)NN * DIM;

    char* ws = (char*)d_ws;
    __hip_bfloat16* whbT = (__hip_bfloat16*)(ws);          // 2 MB
    float* a1g  = (float*)(ws + 0x200000);                 // 32 KB each
    float* a2g  = (float*)(ws + 0x208000);
    float* E1g  = (float*)(ws + 0x210000);
    float* E2g  = (float*)(ws + 0x218000);
    float* w12  = (float*)(ws + 0x220000);                 // 1 KB
    float* crow = (float*)(ws + 0x228000);                 // 128 KB
    unsigned* bm = (unsigned*)(ws + 0x280000);             // 8 MB

    k1_wh<<<NN / 16, 256, 0, stream>>>(h, W, a, whbT, w12);
    k2a_rows<<<NN / 4, 256, 0, stream>>>(h, w12, a1g, a2g, E1g, E2g);
    sa_scan<<<NN / 4, 256, 0, stream>>>(adj, a1g, a2g, E1g, E2g, bm, crow);
    sb_pv<<<NN / 16, 512, 0, stream>>>(bm, crow, a2g, E1g, E2g, whbT, alpha, out);
}

// Round 5
// 238.560 us; speedup vs baseline: 1.9924x; 1.9924x over previous
//
#include <hip/hip_runtime.h>
#include <hip/hip_bf16.h>

#define NN 8192
#define DIM 128
#define KS 4            // split-K factor for PV
#define KSL (NN / KS)   // 2048 k per slice
#define RPB 16          // rows per SB block
#define KC 256          // k-chunk width in SB

typedef __attribute__((ext_vector_type(8))) short bf16x8;
typedef __attribute__((ext_vector_type(4))) float f32x4;
typedef __attribute__((ext_vector_type(4))) int i32x4;
typedef __attribute__((ext_vector_type(4))) unsigned int u32x4;
typedef __attribute__((ext_vector_type(4))) unsigned short u16x4;

static __device__ inline unsigned short f2bf(float x) {
    __hip_bfloat16 b = __float2bfloat16(x);
    return *reinterpret_cast<unsigned short*>(&b);
}

// ---------------------------------------------------------------------------
// K1: Wh = h @ W^T -> whbT (bf16, [DIM][NN] col-major for MFMA B-frags).
// Block 0 additionally computes w12 = {W^T a[:128], W^T a[128:]}.
// ---------------------------------------------------------------------------
__global__ __launch_bounds__(256) void k1_wh(const float* __restrict__ h,
                                             const float* __restrict__ W,
                                             const float* __restrict__ a,
                                             __hip_bfloat16* __restrict__ whbT,
                                             float* __restrict__ w12) {
    __shared__ float WT[128][129];
    __shared__ float h_s[16][128];
    __shared__ float a_sh[256];
    __shared__ __hip_bfloat16 wt_s[128][16];

    const int tid = threadIdx.x;
    const int r0 = blockIdx.x * 16;

    for (int idx = tid; idx < 128 * 128; idx += 256) {
        int d = idx >> 7, k = idx & 127;
        WT[k][d] = W[idx];
    }
    for (int idx = tid; idx < 16 * 128; idx += 256)
        h_s[idx >> 7][idx & 127] = h[(size_t)(r0 + (idx >> 7)) * DIM + (idx & 127)];
    a_sh[tid] = a[tid];
    __syncthreads();

    const int d = tid & 127;
    const int g = tid >> 7;
    float acc[8] = {0, 0, 0, 0, 0, 0, 0, 0};
    for (int k = 0; k < 128; ++k) {
        float wv = WT[k][d];
        #pragma unroll
        for (int rr = 0; rr < 8; ++rr)
            acc[rr] += h_s[g * 8 + rr][k] * wv;
    }
    #pragma unroll
    for (int rr = 0; rr < 8; ++rr)
        wt_s[d][g * 8 + rr] = __float2bfloat16(acc[rr]);

    if (blockIdx.x == 0 && tid < 128) {      // fused k0
        float s1 = 0.f, s2 = 0.f;
        for (int o = 0; o < 128; ++o) {
            float wv = WT[tid][o];
            s1 += wv * a_sh[o];
            s2 += wv * a_sh[128 + o];
        }
        w12[tid] = s1;
        w12[128 + tid] = s2;
    }
    __syncthreads();
    for (int idx = tid; idx < 128 * 16; idx += 256) {
        int dd = idx >> 4, r = idx & 15;
        whbT[(size_t)dd * NN + r0 + r] = wt_s[dd][r];
    }
}

// ---------------------------------------------------------------------------
// K2a: per-row a1 = h.w1, a2 = h.w2, E1 = exp(a2), E2 = exp(0.2 a2)
// ---------------------------------------------------------------------------
__global__ __launch_bounds__(256) void k2a_rows(const float* __restrict__ h,
                                                const float* __restrict__ w12,
                                                float* __restrict__ a1g,
                                                float* __restrict__ a2g,
                                                float* __restrict__ E1g,
                                                float* __restrict__ E2g) {
    const int wid = threadIdx.x >> 6, lane = threadIdx.x & 63;
    const int i = blockIdx.x * 4 + wid;
    const float* hr = h + (size_t)i * DIM;
    float h0 = hr[lane], h1 = hr[lane + 64];
    float s1 = h0 * w12[lane] + h1 * w12[lane + 64];
    float s2 = h0 * w12[128 + lane] + h1 * w12[192 + lane];
    #pragma unroll
    for (int o = 32; o >= 1; o >>= 1) {
        s1 += __shfl_xor(s1, o, 64);
        s2 += __shfl_xor(s2, o, 64);
    }
    if (lane == 0) {
        a1g[i] = s1;
        a2g[i] = s2;
        E1g[i] = expf(s2);
        E2g[i] = expf(0.2f * s2);
    }
}

// ---------------------------------------------------------------------------
// SA: stream adj (1 wave per row, i32x4 16B/lane loads): bitmask + row sums.
// Bit layout: col j -> word (j>>8)*8 + ((j>>7)&1)*4 + (j&3), bit (j>>2)&31.
// No max-shift needed (|a1+a2| bounded); no-neighbor <=> s1+s2==0.
// ---------------------------------------------------------------------------
__global__ __launch_bounds__(256, 8) void sa_scan(const int* __restrict__ adj,
                                                  const float* __restrict__ a1g,
                                                  const float* __restrict__ a2g,
                                                  const float* __restrict__ E1g,
                                                  const float* __restrict__ E2g,
                                                  unsigned* __restrict__ bm,
                                                  float* __restrict__ crow) {
    const int wid = threadIdx.x >> 6, lane = threadIdx.x & 63;
    const int i = blockIdx.x * 4 + wid;
    const float a1i = a1g[i];
    const int* arow = adj + (size_t)i * NN;
    unsigned* brow = bm + (size_t)i * (NN / 32);

    float s1 = 0.f, s2 = 0.f;
    #pragma unroll 2
    for (int it = 0; it < NN / 256; ++it) {
        const int j0 = it * 256 + lane * 4;
        i32x4 v = __builtin_nontemporal_load((const i32x4*)(arow + j0));
        unsigned long long m0 = __ballot(v.x != 0);
        unsigned long long m1 = __ballot(v.y != 0);
        unsigned long long m2 = __ballot(v.z != 0);
        unsigned long long m3 = __ballot(v.w != 0);
        if (lane == 0) {
            u32x4 w;
            w.x = (unsigned)m0; w.y = (unsigned)m1;
            w.z = (unsigned)m2; w.w = (unsigned)m3;
            *(u32x4*)(brow + it * 8) = w;
        } else if (lane == 32) {
            u32x4 w;
            w.x = (unsigned)(m0 >> 32); w.y = (unsigned)(m1 >> 32);
            w.z = (unsigned)(m2 >> 32); w.w = (unsigned)(m3 >> 32);
            *(u32x4*)(brow + it * 8 + 4) = w;
        }
        f32x4 x2 = *(const f32x4*)(a2g + j0);
        f32x4 e1 = *(const f32x4*)(E1g + j0);
        f32x4 e2 = *(const f32x4*)(E2g + j0);
        bool px;
        px = (a1i + x2.x >= 0.f);
        s1 += (v.x && px) ? e1.x : 0.f;  s2 += (v.x && !px) ? e2.x : 0.f;
        px = (a1i + x2.y >= 0.f);
        s1 += (v.y && px) ? e1.y : 0.f;  s2 += (v.y && !px) ? e2.y : 0.f;
        px = (a1i + x2.z >= 0.f);
        s1 += (v.z && px) ? e1.z : 0.f;  s2 += (v.z && !px) ? e2.z : 0.f;
        px = (a1i + x2.w >= 0.f);
        s1 += (v.w && px) ? e1.w : 0.f;  s2 += (v.w && !px) ? e2.w : 0.f;
    }
    #pragma unroll
    for (int o = 32; o >= 1; o >>= 1) {
        s1 += __shfl_xor(s1, o, 64);
        s2 += __shfl_xor(s2, o, 64);
    }
    if (lane == 0) {
        float c1 = 0.f, c2 = 0.f;
        if (s1 + s2 > 0.f) {
            float e1v = expf(a1i);
            float e2v = expf(0.2f * a1i);
            float S = e1v * s1 + e2v * s2;
            c1 = e1v / S;
            c2 = e2v / S;
        }
        crow[i * 4 + 0] = c1;
        crow[i * 4 + 1] = c2;
        crow[i * 4 + 2] = a1i;
        crow[i * 4 + 3] = 0.f;
    }
}

// ---------------------------------------------------------------------------
// SB: fused alpha-write + PV MFMA, split-K. grid (NN/16, KS), 256 threads
// (4 waves) -> 8 blocks/CU, 32 waves/CU, ~11 KB LDS, 4-wave barrier scope.
// Per 256-col chunk: compute 16x256 alpha (coalesced NT f32 store + bf16 LDS
// stage, double-buffered), then each wave MFMAs its 32 output dims.
// ---------------------------------------------------------------------------
__global__ __launch_bounds__(256, 8) void sb_pv(const unsigned* __restrict__ bm,
                                                const float* __restrict__ crowG,
                                                const float* __restrict__ a2g,
                                                const float* __restrict__ E1g,
                                                const float* __restrict__ E2g,
                                                const __hip_bfloat16* __restrict__ whbT,
                                                float* __restrict__ alpha,
                                                float* __restrict__ part) {
    __shared__ unsigned bmL[RPB][KSL / 32];              // 4 KB
    __shared__ __hip_bfloat16 abuf[2][RPB][KC + 8];      // 16.5 KB
    __shared__ float crowL[RPB][4];                      // 256 B

    const int tid = threadIdx.x;
    const int wv = tid >> 6, lane = tid & 63;
    const int r0 = blockIdx.x * RPB;
    const int ks = blockIdx.y;
    const int k0 = ks * KSL;

    {   // preload bitmask slice + row coefficients
        const int r = tid >> 4, wq = (tid & 15) << 2;    // 16 rows x 16 quads
        *(u32x4*)(&bmL[r][wq]) =
            *(const u32x4*)(bm + (size_t)(r0 + r) * (NN / 32) + ks * (KSL / 32) + wq);
        if (tid < RPB * 4)
            crowL[tid >> 2][tid & 3] = crowG[(r0 + (tid >> 2)) * 4 + (tid & 3)];
    }
    __syncthreads();

    f32x4 acc0 = (f32x4){0.f, 0.f, 0.f, 0.f};
    f32x4 acc1 = (f32x4){0.f, 0.f, 0.f, 0.f};
    const int n0 = wv * 32;
    const short* wb = reinterpret_cast<const short*>(whbT);
    const short* bptr0 = wb + (size_t)(n0 + (lane & 15)) * NN + k0 + 8 * (lane >> 4);
    const short* bptr1 = wb + (size_t)(n0 + 16 + (lane & 15)) * NN + k0 + 8 * (lane >> 4);

    for (int kc = 0; kc < KSL; kc += KC) {
        const int dbuf = (kc >> 8) & 1;
        #pragma unroll
        for (int v = 0; v < 4; ++v) {
            const int vid = v * 256 + tid;
            const int r = vid >> 6;                      // 64 threads per row
            const int c4 = (vid & 63) << 2;
            const int jl = kc + c4;                      // col within slice
            const int j = k0 + jl;                       // global col
            const int wbw = ((jl >> 8) << 3) + (((jl >> 7) & 1) << 2);
            i32x4 w4 = *(const i32x4*)(&bmL[r][wbw]);
            const unsigned p = (jl >> 2) & 31;
            const float c1 = crowL[r][0], c2 = crowL[r][1], a1i = crowL[r][2];
            f32x4 x2 = *(const f32x4*)(a2g + j);
            f32x4 e1 = *(const f32x4*)(E1g + j);
            f32x4 e2 = *(const f32x4*)(E2g + j);
            f32x4 al;
            al.x = ((w4.x >> p) & 1) ? ((a1i + x2.x >= 0.f) ? c1 * e1.x : c2 * e2.x) : 0.f;
            al.y = ((w4.y >> p) & 1) ? ((a1i + x2.y >= 0.f) ? c1 * e1.y : c2 * e2.y) : 0.f;
            al.z = ((w4.z >> p) & 1) ? ((a1i + x2.z >= 0.f) ? c1 * e1.z : c2 * e2.z) : 0.f;
            al.w = ((w4.w >> p) & 1) ? ((a1i + x2.w >= 0.f) ? c1 * e1.w : c2 * e2.w) : 0.f;
            __builtin_nontemporal_store(al, (f32x4*)(alpha + (size_t)(r0 + r) * NN + j));
            u16x4 ub;
            ub.x = f2bf(al.x); ub.y = f2bf(al.y); ub.z = f2bf(al.z); ub.w = f2bf(al.w);
            *(u16x4*)(&abuf[dbuf][r][c4]) = ub;
        }
        __syncthreads();
        #pragma unroll
        for (int kk = 0; kk < KC; kk += 32) {
            bf16x8 af = *(const bf16x8*)(&abuf[dbuf][lane & 15][kk + 8 * (lane >> 4)]);
            bf16x8 b0 = *(const bf16x8*)(bptr0 + kc + kk);
            bf16x8 b1 = *(const bf16x8*)(bptr1 + kc + kk);
            acc0 = __builtin_amdgcn_mfma_f32_16x16x32_bf16(af, b0, acc0, 0, 0, 0);
            acc1 = __builtin_amdgcn_mfma_f32_16x16x32_bf16(af, b1, acc1, 0, 0, 0);
        }
    }

    float* pb = part + (size_t)ks * NN * DIM;
    const int rb = (lane >> 4) * 4;
    #pragma unroll
    for (int q = 0; q < 4; ++q) {
        pb[(size_t)(r0 + rb + q) * DIM + n0 + (lane & 15)] = acc0[q];
        pb[(size_t)(r0 + rb + q) * DIM + n0 + 16 + (lane & 15)] = acc1[q];
    }
}

// ---------------------------------------------------------------------------
// K5: reduce split-K partials -> out (vectorized)
// ---------------------------------------------------------------------------
__global__ __launch_bounds__(256) void k5_reduce(const float* __restrict__ part,
                                                 float* __restrict__ out) {
    const size_t idx = ((size_t)blockIdx.x * 256 + threadIdx.x) * 4;
    f32x4 s = (f32x4){0.f, 0.f, 0.f, 0.f};
    #pragma unroll
    for (int ks = 0; ks < KS; ++ks)
        s += *(const f32x4*)(part + (size_t)ks * NN * DIM + idx);
    *(f32x4*)(out + idx) = s;
}

// ---------------------------------------------------------------------------
extern "C" void kernel_launch(void* const* d_in, const int* in_sizes, int n_in,
                              void* d_out, int out_size, void* d_ws, size_t ws_size,
                              hipStream_t stream) {
    const float* h   = (const float*)d_in[0];
    const int*   adj = (const int*)d_in[1];
    const float* W   = (const float*)d_in[2];
    const float* a   = (const float*)d_in[3];

    float* out   = (float*)d_out;
    float* alpha = out + (size_t)NN * DIM;

    char* ws = (char*)d_ws;
    __hip_bfloat16* whbT = (__hip_bfloat16*)(ws);          // 2 MB
    float* a1g  = (float*)(ws + 0x200000);                 // 32 KB each
    float* a2g  = (float*)(ws + 0x208000);
    float* E1g  = (float*)(ws + 0x210000);
    float* E2g  = (float*)(ws + 0x218000);
    float* w12  = (float*)(ws + 0x220000);                 // 1 KB
    float* crow = (float*)(ws + 0x228000);                 // 128 KB
    unsigned* bm = (unsigned*)(ws + 0x280000);             // 8 MB
    float* part = (float*)(ws + 0xA80000);                 // 16 MB

    k1_wh<<<NN / 16, 256, 0, stream>>>(h, W, a, whbT, w12);
    k2a_rows<<<NN / 4, 256, 0, stream>>>(h, w12, a1g, a2g, E1g, E2g);
    sa_scan<<<NN / 4, 256, 0, stream>>>(adj, a1g, a2g, E1g, E2g, bm, crow);
    sb_pv<<<dim3(NN / RPB, KS), 256, 0, stream>>>(bm, crow, a2g, E1g, E2g, whbT, alpha, part);
    k5_reduce<<<NN * DIM / 1024, 256, 0, stream>>>(part, out);
}

// Round 6
// 199.637 us; speedup vs baseline: 2.3808x; 1.1950x over previous
//
#include <hip/hip_runtime.h>
#include <hip/hip_bf16.h>

#define NN 8192
#define DIM 128
#define KS 8            // split-K factor for PV
#define KSL (NN / KS)   // 1024 k per slice
#define RPB 64          // rows per SB block
#define KC 128          // k-chunk width in SB

typedef __attribute__((ext_vector_type(8))) short bf16x8;
typedef __attribute__((ext_vector_type(4))) float f32x4;
typedef __attribute__((ext_vector_type(4))) int i32x4;
typedef __attribute__((ext_vector_type(4))) unsigned int u32x4;
typedef __attribute__((ext_vector_type(4))) unsigned short u16x4;

static __device__ inline unsigned short f2bf(float x) {
    __hip_bfloat16 b = __float2bfloat16(x);
    return *reinterpret_cast<unsigned short*>(&b);
}

// ---------------------------------------------------------------------------
// K1: Wh = h @ W^T -> whbT_t (bf16, tiled [k/8][128 dims][8k] so a wave's
// B-frag load is 256B-contiguous segments). Block 0 also computes
// w12 = {W^T a[:128], W^T a[128:]}.
// ---------------------------------------------------------------------------
__global__ __launch_bounds__(256) void k1_wh(const float* __restrict__ h,
                                             const float* __restrict__ W,
                                             const float* __restrict__ a,
                                             __hip_bfloat16* __restrict__ whbT,
                                             float* __restrict__ w12) {
    __shared__ float WT[128][129];
    __shared__ float h_s[16][128];
    __shared__ float a_sh[256];
    __shared__ __hip_bfloat16 wt_s[128][16];

    const int tid = threadIdx.x;
    const int r0 = blockIdx.x * 16;

    for (int idx = tid; idx < 128 * 128; idx += 256) {
        int d = idx >> 7, k = idx & 127;
        WT[k][d] = W[idx];
    }
    for (int idx = tid; idx < 16 * 128; idx += 256)
        h_s[idx >> 7][idx & 127] = h[(size_t)(r0 + (idx >> 7)) * DIM + (idx & 127)];
    a_sh[tid] = a[tid];
    __syncthreads();

    const int d = tid & 127;
    const int g = tid >> 7;
    float acc[8] = {0, 0, 0, 0, 0, 0, 0, 0};
    for (int k = 0; k < 128; ++k) {
        float wv = WT[k][d];
        #pragma unroll
        for (int rr = 0; rr < 8; ++rr)
            acc[rr] += h_s[g * 8 + rr][k] * wv;
    }
    #pragma unroll
    for (int rr = 0; rr < 8; ++rr)
        wt_s[d][g * 8 + rr] = __float2bfloat16(acc[rr]);

    if (blockIdx.x == 0 && tid < 128) {      // fused k0
        float s1 = 0.f, s2 = 0.f;
        for (int o = 0; o < 128; ++o) {
            float wv = WT[tid][o];
            s1 += wv * a_sh[o];
            s2 += wv * a_sh[128 + o];
        }
        w12[tid] = s1;
        w12[128 + tid] = s2;
    }
    __syncthreads();
    // tiled write: dst[(k>>3)*1024 + d*8 + (k&7)], k = r0 + local row
    for (int idx = tid; idx < 2048; idx += 256) {
        const int kb2 = idx >> 10;           // 0/1 (8-row k-subblock)
        const int rem = idx & 1023;          // d*8 + ke
        const int dd = rem >> 3, ke = rem & 7;
        whbT[((r0 >> 3) + kb2) * 1024 + rem] = wt_s[dd][kb2 * 8 + ke];
    }
}

// ---------------------------------------------------------------------------
// K2a: per-row a1 = h.w1, a2 = h.w2, E1 = exp(a2), E2 = exp(0.2 a2)
// ---------------------------------------------------------------------------
__global__ __launch_bounds__(256) void k2a_rows(const float* __restrict__ h,
                                                const float* __restrict__ w12,
                                                float* __restrict__ a1g,
                                                float* __restrict__ a2g,
                                                float* __restrict__ E1g,
                                                float* __restrict__ E2g) {
    const int wid = threadIdx.x >> 6, lane = threadIdx.x & 63;
    const int i = blockIdx.x * 4 + wid;
    const float* hr = h + (size_t)i * DIM;
    float h0 = hr[lane], h1 = hr[lane + 64];
    float s1 = h0 * w12[lane] + h1 * w12[lane + 64];
    float s2 = h0 * w12[128 + lane] + h1 * w12[192 + lane];
    #pragma unroll
    for (int o = 32; o >= 1; o >>= 1) {
        s1 += __shfl_xor(s1, o, 64);
        s2 += __shfl_xor(s2, o, 64);
    }
    if (lane == 0) {
        a1g[i] = s1;
        a2g[i] = s2;
        E1g[i] = expf(s2);
        E2g[i] = expf(0.2f * s2);
    }
}

// ---------------------------------------------------------------------------
// SA: stream adj (1 wave per row, i32x4 16B/lane loads): bitmask + row sums.
// Bit layout: col j -> word (j>>8)*8 + ((j>>7)&1)*4 + (j&3), bit (j>>2)&31.
// No max-shift needed (|a1+a2| bounded); no-neighbor <=> s1+s2==0.
// ---------------------------------------------------------------------------
__global__ __launch_bounds__(256, 8) void sa_scan(const int* __restrict__ adj,
                                                  const float* __restrict__ a1g,
                                                  const float* __restrict__ a2g,
                                                  const float* __restrict__ E1g,
                                                  const float* __restrict__ E2g,
                                                  unsigned* __restrict__ bm,
                                                  float* __restrict__ crow) {
    const int wid = threadIdx.x >> 6, lane = threadIdx.x & 63;
    const int i = blockIdx.x * 4 + wid;
    const float a1i = a1g[i];
    const int* arow = adj + (size_t)i * NN;
    unsigned* brow = bm + (size_t)i * (NN / 32);

    float s1 = 0.f, s2 = 0.f;
    #pragma unroll 2
    for (int it = 0; it < NN / 256; ++it) {
        const int j0 = it * 256 + lane * 4;
        i32x4 v = __builtin_nontemporal_load((const i32x4*)(arow + j0));
        unsigned long long m0 = __ballot(v.x != 0);
        unsigned long long m1 = __ballot(v.y != 0);
        unsigned long long m2 = __ballot(v.z != 0);
        unsigned long long m3 = __ballot(v.w != 0);
        if (lane == 0) {
            u32x4 w;
            w.x = (unsigned)m0; w.y = (unsigned)m1;
            w.z = (unsigned)m2; w.w = (unsigned)m3;
            *(u32x4*)(brow + it * 8) = w;
        } else if (lane == 32) {
            u32x4 w;
            w.x = (unsigned)(m0 >> 32); w.y = (unsigned)(m1 >> 32);
            w.z = (unsigned)(m2 >> 32); w.w = (unsigned)(m3 >> 32);
            *(u32x4*)(brow + it * 8 + 4) = w;
        }
        f32x4 x2 = *(const f32x4*)(a2g + j0);
        f32x4 e1 = *(const f32x4*)(E1g + j0);
        f32x4 e2 = *(const f32x4*)(E2g + j0);
        bool px;
        px = (a1i + x2.x >= 0.f);
        s1 += (v.x && px) ? e1.x : 0.f;  s2 += (v.x && !px) ? e2.x : 0.f;
        px = (a1i + x2.y >= 0.f);
        s1 += (v.y && px) ? e1.y : 0.f;  s2 += (v.y && !px) ? e2.y : 0.f;
        px = (a1i + x2.z >= 0.f);
        s1 += (v.z && px) ? e1.z : 0.f;  s2 += (v.z && !px) ? e2.z : 0.f;
        px = (a1i + x2.w >= 0.f);
        s1 += (v.w && px) ? e1.w : 0.f;  s2 += (v.w && !px) ? e2.w : 0.f;
    }
    #pragma unroll
    for (int o = 32; o >= 1; o >>= 1) {
        s1 += __shfl_xor(s1, o, 64);
        s2 += __shfl_xor(s2, o, 64);
    }
    if (lane == 0) {
        float c1 = 0.f, c2 = 0.f;
        if (s1 + s2 > 0.f) {
            float e1v = expf(a1i);
            float e2v = expf(0.2f * a1i);
            float S = e1v * s1 + e2v * s2;
            c1 = e1v / S;
            c2 = e2v / S;
        }
        crow[i * 4 + 0] = c1;
        crow[i * 4 + 1] = c2;
        crow[i * 4 + 2] = a1i;
        crow[i * 4 + 3] = 0.f;
    }
}

// ---------------------------------------------------------------------------
// SB: fused alpha-write + PV MFMA, split-K. grid (NN/64, KS=8), 512 threads.
// RPB=64 rows per block -> 4x B-frag reuse (1 B load feeds 4 row-tile MFMAs);
// whbT L2 gather = 256 MB total. KC=128 chunks, double-buffered bf16 stage.
// ---------------------------------------------------------------------------
__global__ __launch_bounds__(512, 6) void sb_pv(const unsigned* __restrict__ bm,
                                                const float* __restrict__ crowG,
                                                const float* __restrict__ a2g,
                                                const float* __restrict__ E1g,
                                                const float* __restrict__ E2g,
                                                const __hip_bfloat16* __restrict__ whbT,
                                                float* __restrict__ alpha,
                                                float* __restrict__ part) {
    __shared__ unsigned bmL[RPB][KSL / 32];              // 64 x 32 words = 8 KB
    __shared__ __hip_bfloat16 abuf[2][RPB][KC + 8];      // 34.8 KB
    __shared__ float crowL[RPB][4];                      // 1 KB

    const int tid = threadIdx.x;
    const int wv = tid >> 6, lane = tid & 63;
    const int r0 = blockIdx.x * RPB;
    const int ks = blockIdx.y;
    const int k0 = ks * KSL;

    {   // preload bitmask slice + row coefficients
        const int r = tid >> 3, wq = (tid & 7) << 2;     // 64 rows x 8 quads
        *(u32x4*)(&bmL[r][wq]) =
            *(const u32x4*)(bm + (size_t)(r0 + r) * (NN / 32) + ks * (KSL / 32) + wq);
        if (tid < RPB * 4)
            crowL[tid >> 2][tid & 3] = crowG[(r0 + (tid >> 2)) * 4 + (tid & 3)];
    }
    __syncthreads();

    f32x4 acc[4];
    #pragma unroll
    for (int rt = 0; rt < 4; ++rt) acc[rt] = (f32x4){0.f, 0.f, 0.f, 0.f};
    const int n0 = wv * 16;
    const short* wb = reinterpret_cast<const short*>(whbT);
    // tiled whbT: elem = ((k>>3)*128 + d)*8 + (k&7); wave B-frag base:
    const short* bbase = wb + (size_t)(n0 + (lane & 15)) * 8 + (size_t)(lane >> 4) * 1024;

    for (int kc = 0; kc < KSL; kc += KC) {
        const int dbuf = (kc >> 7) & 1;
        #pragma unroll
        for (int v = 0; v < 4; ++v) {
            const int vid = v * 512 + tid;
            const int r = vid >> 5;                      // 32 threads per row
            const int c4 = (vid & 31) << 2;
            const int jl = kc + c4;                      // col within slice
            const int j = k0 + jl;                       // global col
            const int wbw = ((jl >> 8) << 3) + (((jl >> 7) & 1) << 2);
            i32x4 w4 = *(const i32x4*)(&bmL[r][wbw]);
            const unsigned p = (jl >> 2) & 31;
            const float c1 = crowL[r][0], c2 = crowL[r][1], a1i = crowL[r][2];
            f32x4 x2 = *(const f32x4*)(a2g + j);
            f32x4 e1 = *(const f32x4*)(E1g + j);
            f32x4 e2 = *(const f32x4*)(E2g + j);
            f32x4 al;
            al.x = ((w4.x >> p) & 1) ? ((a1i + x2.x >= 0.f) ? c1 * e1.x : c2 * e2.x) : 0.f;
            al.y = ((w4.y >> p) & 1) ? ((a1i + x2.y >= 0.f) ? c1 * e1.y : c2 * e2.y) : 0.f;
            al.z = ((w4.z >> p) & 1) ? ((a1i + x2.z >= 0.f) ? c1 * e1.z : c2 * e2.z) : 0.f;
            al.w = ((w4.w >> p) & 1) ? ((a1i + x2.w >= 0.f) ? c1 * e1.w : c2 * e2.w) : 0.f;
            __builtin_nontemporal_store(al, (f32x4*)(alpha + (size_t)(r0 + r) * NN + j));
            u16x4 ub;
            ub.x = f2bf(al.x); ub.y = f2bf(al.y); ub.z = f2bf(al.z); ub.w = f2bf(al.w);
            *(u16x4*)(&abuf[dbuf][r][c4]) = ub;
        }
        __syncthreads();
        #pragma unroll
        for (int kk = 0; kk < KC; kk += 32) {
            // one B-frag, reused across 4 row-tiles
            bf16x8 bf = *(const bf16x8*)(bbase + (size_t)((k0 + kc + kk) >> 3) * 1024);
            #pragma unroll
            for (int rt = 0; rt < 4; ++rt) {
                bf16x8 af = *(const bf16x8*)(&abuf[dbuf][rt * 16 + (lane & 15)][kk + 8 * (lane >> 4)]);
                acc[rt] = __builtin_amdgcn_mfma_f32_16x16x32_bf16(af, bf, acc[rt], 0, 0, 0);
            }
        }
    }

    float* pb = part + (size_t)ks * NN * DIM;
    const int rb = (lane >> 4) * 4;
    #pragma unroll
    for (int rt = 0; rt < 4; ++rt) {
        #pragma unroll
        for (int q = 0; q < 4; ++q)
            __builtin_nontemporal_store(acc[rt][q],
                pb + (size_t)(r0 + rt * 16 + rb + q) * DIM + n0 + (lane & 15));
    }
}

// ---------------------------------------------------------------------------
// K5: reduce split-K partials -> out (vectorized, NT reads)
// ---------------------------------------------------------------------------
__global__ __launch_bounds__(256) void k5_reduce(const float* __restrict__ part,
                                                 float* __restrict__ out) {
    const size_t idx = ((size_t)blockIdx.x * 256 + threadIdx.x) * 4;
    f32x4 s = (f32x4){0.f, 0.f, 0.f, 0.f};
    #pragma unroll
    for (int ks = 0; ks < KS; ++ks)
        s += __builtin_nontemporal_load((const f32x4*)(part + (size_t)ks * NN * DIM + idx));
    *(f32x4*)(out + idx) = s;
}

// ---------------------------------------------------------------------------
extern "C" void kernel_launch(void* const* d_in, const int* in_sizes, int n_in,
                              void* d_out, int out_size, void* d_ws, size_t ws_size,
                              hipStream_t stream) {
    const float* h   = (const float*)d_in[0];
    const int*   adj = (const int*)d_in[1];
    const float* W   = (const float*)d_in[2];
    const float* a   = (const float*)d_in[3];

    float* out   = (float*)d_out;
    float* alpha = out + (size_t)NN * DIM;

    char* ws = (char*)d_ws;
    __hip_bfloat16* whbT = (__hip_bfloat16*)(ws);          // 2 MB
    float* a1g  = (float*)(ws + 0x200000);                 // 32 KB each
    float* a2g  = (float*)(ws + 0x208000);
    float* E1g  = (float*)(ws + 0x210000);
    float* E2g  = (float*)(ws + 0x218000);
    float* w12  = (float*)(ws + 0x220000);                 // 1 KB
    float* crow = (float*)(ws + 0x228000);                 // 128 KB
    unsigned* bm = (unsigned*)(ws + 0x280000);             // 8 MB
    float* part = (float*)(ws + 0xA80000);                 // KS*4 MB = 32 MB

    k1_wh<<<NN / 16, 256, 0, stream>>>(h, W, a, whbT, w12);
    k2a_rows<<<NN / 4, 256, 0, stream>>>(h, w12, a1g, a2g, E1g, E2g);
    sa_scan<<<NN / 4, 256, 0, stream>>>(adj, a1g, a2g, E1g, E2g, bm, crow);
    sb_pv<<<dim3(NN / RPB, KS), 512, 0, stream>>>(bm, crow, a2g, E1g, E2g, whbT, alpha, part);
    k5_reduce<<<NN * DIM / 1024, 256, 0, stream>>>(part, out);
}

// Round 8
// 183.504 us; speedup vs baseline: 2.5901x; 1.0879x over previous
//
#include <hip/hip_runtime.h>
#include <hip/hip_bf16.h>

#define NN 8192
#define DIM 128
#define KS 8            // split-K factor for PV
#define KSL (NN / KS)   // 1024 k per slice
#define RPB 64          // rows per SB block
#define KC 128          // k-chunk width in SB

typedef __attribute__((ext_vector_type(8))) short bf16x8;
typedef __attribute__((ext_vector_type(4))) float f32x4;
typedef __attribute__((ext_vector_type(4))) int i32x4;
typedef __attribute__((ext_vector_type(4))) unsigned int u32x4;
typedef __attribute__((ext_vector_type(4))) unsigned short u16x4;
typedef __attribute__((ext_vector_type(4))) short s16x4;

static __device__ inline unsigned short f2bf(float x) {
    __hip_bfloat16 b = __float2bfloat16(x);
    return *reinterpret_cast<unsigned short*>(&b);
}

struct BSplit { short hi, lo; };
static __device__ inline BSplit bsplit(float x) {
    BSplit r;
    __hip_bfloat16 h = __float2bfloat16(x);
    r.hi = *reinterpret_cast<short*>(&h);
    float rem = x - __bfloat162float(h);
    __hip_bfloat16 l = __float2bfloat16(rem);
    r.lo = *reinterpret_cast<short*>(&l);
    return r;
}

// ---------------------------------------------------------------------------
// K1M: one kernel for Wh = h@W^T (split-bf16 MFMA, f32-grade accuracy),
// a1/a2 (reduced from the f32 accumulators), packed tables
// pk[i] = {a2, bf16(E1)|bf16(E2)<<16}, and whbT (bf16, tiled
// [k>>3][dim][k&7] for SB's B-frags). grid 128 blocks x 64 rows, 4 waves.
// ---------------------------------------------------------------------------
__global__ __launch_bounds__(256) void k1m(const float* __restrict__ h,
                                           const float* __restrict__ W,
                                           const float* __restrict__ a,
                                           __hip_bfloat16* __restrict__ whbT,
                                           float* __restrict__ a1g,
                                           float2* __restrict__ pk) {
    __shared__ short whi[128 * 132];         // W hi, row stride 132 (264B)
    __shared__ short wlo[128 * 132];         // W lo
    __shared__ short wt[8 * 128 * 8];        // whbT retile staging (16 KB)
    __shared__ float a_sh[256];

    const int tid = threadIdx.x;
    const int wv = tid >> 6, lane = tid & 63;
    const int r0 = blockIdx.x * 64;

    for (int idx = tid; idx < 128 * 128; idx += 256) {
        const int d = idx >> 7, k = idx & 127;
        BSplit s = bsplit(W[idx]);
        whi[d * 132 + k] = s.hi;
        wlo[d * 132 + k] = s.lo;
    }
    a_sh[tid] = a[tid];
    __syncthreads();

    f32x4 acc[8];
    #pragma unroll
    for (int n = 0; n < 8; ++n) acc[n] = (f32x4){0.f, 0.f, 0.f, 0.f};

    const int arow = r0 + wv * 16 + (lane & 15);
    const int ksub = (lane >> 4) * 8;
    const float* hp = h + (size_t)arow * DIM + ksub;

    #pragma unroll
    for (int kk = 0; kk < 128; kk += 32) {
        f32x4 x0 = *(const f32x4*)(hp + kk);
        f32x4 x1 = *(const f32x4*)(hp + kk + 4);
        bf16x8 ah, al;
        {
            BSplit s0 = bsplit(x0.x), s1 = bsplit(x0.y), s2 = bsplit(x0.z), s3 = bsplit(x0.w);
            BSplit s4 = bsplit(x1.x), s5 = bsplit(x1.y), s6 = bsplit(x1.z), s7 = bsplit(x1.w);
            ah[0] = s0.hi; al[0] = s0.lo; ah[1] = s1.hi; al[1] = s1.lo;
            ah[2] = s2.hi; al[2] = s2.lo; ah[3] = s3.hi; al[3] = s3.lo;
            ah[4] = s4.hi; al[4] = s4.lo; ah[5] = s5.hi; al[5] = s5.lo;
            ah[6] = s6.hi; al[6] = s6.lo; ah[7] = s7.hi; al[7] = s7.lo;
        }
        #pragma unroll
        for (int n = 0; n < 8; ++n) {
            const int boff = (n * 16 + (lane & 15)) * 132 + kk + ksub;
            bf16x8 bh = *(const bf16x8*)(whi + boff);
            bf16x8 bl = *(const bf16x8*)(wlo + boff);
            acc[n] = __builtin_amdgcn_mfma_f32_16x16x32_bf16(ah, bh, acc[n], 0, 0, 0);
            acc[n] = __builtin_amdgcn_mfma_f32_16x16x32_bf16(ah, bl, acc[n], 0, 0, 0);
            acc[n] = __builtin_amdgcn_mfma_f32_16x16x32_bf16(al, bh, acc[n], 0, 0, 0);
        }
    }

    // a1/a2 from f32 accumulators: lane partial over its 8 n-tiles, then
    // shuffle-reduce across the 16 lanes sharing each output row.
    float p1[4] = {0.f, 0.f, 0.f, 0.f}, p2[4] = {0.f, 0.f, 0.f, 0.f};
    #pragma unroll
    for (int n = 0; n < 8; ++n) {
        const float av1 = a_sh[n * 16 + (lane & 15)];
        const float av2 = a_sh[128 + n * 16 + (lane & 15)];
        #pragma unroll
        for (int q = 0; q < 4; ++q) {
            p1[q] += acc[n][q] * av1;
            p2[q] += acc[n][q] * av2;
        }
    }
    #pragma unroll
    for (int o = 8; o >= 1; o >>= 1) {
        #pragma unroll
        for (int q = 0; q < 4; ++q) {
            p1[q] += __shfl_xor(p1[q], o, 64);
            p2[q] += __shfl_xor(p2[q], o, 64);
        }
    }
    if ((lane & 15) == 0) {
        #pragma unroll
        for (int q = 0; q < 4; ++q) {
            const int row = r0 + wv * 16 + (lane >> 4) * 4 + q;
            a1g[row] = p1[q];
            const float E1v = expf(p2[q]);
            const float E2v = expf(0.2f * p2[q]);
            unsigned ub = (unsigned)f2bf(E1v) | ((unsigned)f2bf(E2v) << 16);
            float2 pv;
            pv.x = p2[q];
            pv.y = __uint_as_float(ub);
            pk[row] = pv;
        }
    }

    // whbT retile: acc -> wt (LDS) -> contiguous 16 KB global block
    #pragma unroll
    for (int n = 0; n < 8; ++n) {
        #pragma unroll
        for (int q = 0; q < 4; ++q) {
            const int kloc = wv * 16 + (lane >> 4) * 4 + q;   // block-local k
            const int d = n * 16 + (lane & 15);
            wt[(kloc >> 3) * 1024 + d * 8 + (kloc & 7)] = (short)f2bf(acc[n][q]);
        }
    }
    __syncthreads();
    short* dst = reinterpret_cast<short*>(whbT) + ((size_t)r0 << 7);
    for (int idx = tid * 4; idx < 8192; idx += 1024)
        *(s16x4*)(dst + idx) = *(const s16x4*)(wt + idx);
}

// ---------------------------------------------------------------------------
// SA: stream adj (1 wave per row, i32x4 16B/lane NT loads): bitmask + row
// softmax sums from packed tables. Bit layout: col j -> word
// (j>>8)*8 + ((j>>7)&1)*4 + (j&3), bit (j>>2)&31.
// No max-shift needed (|a1+a2| bounded); no-neighbor <=> s1+s2==0.
// ---------------------------------------------------------------------------
__global__ __launch_bounds__(256, 8) void sa_scan(const int* __restrict__ adj,
                                                  const float* __restrict__ a1g,
                                                  const float2* __restrict__ pk,
                                                  unsigned* __restrict__ bm,
                                                  float* __restrict__ crow) {
    const int wid = threadIdx.x >> 6, lane = threadIdx.x & 63;
    const int i = blockIdx.x * 4 + wid;
    const float a1i = a1g[i];
    const int* arow = adj + (size_t)i * NN;
    unsigned* brow = bm + (size_t)i * (NN / 32);
    const float* pkf = reinterpret_cast<const float*>(pk);

    float s1 = 0.f, s2 = 0.f;
    #pragma unroll 2
    for (int it = 0; it < NN / 256; ++it) {
        const int j0 = it * 256 + lane * 4;
        i32x4 v = __builtin_nontemporal_load((const i32x4*)(arow + j0));
        unsigned long long m0 = __ballot(v.x != 0);
        unsigned long long m1 = __ballot(v.y != 0);
        unsigned long long m2 = __ballot(v.z != 0);
        unsigned long long m3 = __ballot(v.w != 0);
        if (lane == 0) {
            u32x4 w;
            w.x = (unsigned)m0; w.y = (unsigned)m1;
            w.z = (unsigned)m2; w.w = (unsigned)m3;
            *(u32x4*)(brow + it * 8) = w;
        } else if (lane == 32) {
            u32x4 w;
            w.x = (unsigned)(m0 >> 32); w.y = (unsigned)(m1 >> 32);
            w.z = (unsigned)(m2 >> 32); w.w = (unsigned)(m3 >> 32);
            *(u32x4*)(brow + it * 8 + 4) = w;
        }
        f32x4 pa = *(const f32x4*)(pkf + 2 * j0);
        f32x4 pb = *(const f32x4*)(pkf + 2 * j0 + 4);
        float x2, e1, e2; unsigned ub; bool px;

        x2 = pa.x; ub = __float_as_uint(pa.y);
        e1 = __uint_as_float(ub << 16); e2 = __uint_as_float(ub & 0xffff0000u);
        px = (a1i + x2 >= 0.f);
        s1 += (v.x && px) ? e1 : 0.f;  s2 += (v.x && !px) ? e2 : 0.f;

        x2 = pa.z; ub = __float_as_uint(pa.w);
        e1 = __uint_as_float(ub << 16); e2 = __uint_as_float(ub & 0xffff0000u);
        px = (a1i + x2 >= 0.f);
        s1 += (v.y && px) ? e1 : 0.f;  s2 += (v.y && !px) ? e2 : 0.f;

        x2 = pb.x; ub = __float_as_uint(pb.y);
        e1 = __uint_as_float(ub << 16); e2 = __uint_as_float(ub & 0xffff0000u);
        px = (a1i + x2 >= 0.f);
        s1 += (v.z && px) ? e1 : 0.f;  s2 += (v.z && !px) ? e2 : 0.f;

        x2 = pb.z; ub = __float_as_uint(pb.w);
        e1 = __uint_as_float(ub << 16); e2 = __uint_as_float(ub & 0xffff0000u);
        px = (a1i + x2 >= 0.f);
        s1 += (v.w && px) ? e1 : 0.f;  s2 += (v.w && !px) ? e2 : 0.f;
    }
    #pragma unroll
    for (int o = 32; o >= 1; o >>= 1) {
        s1 += __shfl_xor(s1, o, 64);
        s2 += __shfl_xor(s2, o, 64);
    }
    if (lane == 0) {
        float c1 = 0.f, c2 = 0.f;
        if (s1 + s2 > 0.f) {
            float e1v = expf(a1i);
            float e2v = expf(0.2f * a1i);
            float S = e1v * s1 + e2v * s2;
            c1 = e1v / S;
            c2 = e2v / S;
        }
        crow[i * 4 + 0] = c1;
        crow[i * 4 + 1] = c2;
        crow[i * 4 + 2] = a1i;
        crow[i * 4 + 3] = 0.f;
    }
}

// ---------------------------------------------------------------------------
// SB: fused alpha-write + PV MFMA, split-K. grid (NN/64, KS=8), 512 threads.
// RPB=64 rows per block -> 4x B-frag reuse; whbT L2 gather = 256 MB total.
// KC=128 chunks, double-buffered bf16 stage, 1 barrier per chunk.
// ---------------------------------------------------------------------------
__global__ __launch_bounds__(512, 6) void sb_pv(const unsigned* __restrict__ bm,
                                                const float* __restrict__ crowG,
                                                const float2* __restrict__ pk,
                                                const __hip_bfloat16* __restrict__ whbT,
                                                float* __restrict__ alpha,
                                                float* __restrict__ part) {
    __shared__ unsigned bmL[RPB][KSL / 32];              // 8 KB
    __shared__ __hip_bfloat16 abuf[2][RPB][KC + 8];      // 34.8 KB
    __shared__ float crowL[RPB][4];                      // 1 KB

    const int tid = threadIdx.x;
    const int wv = tid >> 6, lane = tid & 63;
    const int r0 = blockIdx.x * RPB;
    const int ks = blockIdx.y;
    const int k0 = ks * KSL;
    const float* pkf = reinterpret_cast<const float*>(pk);

    {   // preload bitmask slice + row coefficients
        const int r = tid >> 3, wq = (tid & 7) << 2;     // 64 rows x 8 quads
        *(u32x4*)(&bmL[r][wq]) =
            *(const u32x4*)(bm + (size_t)(r0 + r) * (NN / 32) + ks * (KSL / 32) + wq);
        if (tid < RPB * 4)
            crowL[tid >> 2][tid & 3] = crowG[(r0 + (tid >> 2)) * 4 + (tid & 3)];
    }
    __syncthreads();

    f32x4 acc[4];
    #pragma unroll
    for (int rt = 0; rt < 4; ++rt) acc[rt] = (f32x4){0.f, 0.f, 0.f, 0.f};
    const int n0 = wv * 16;
    const short* wb = reinterpret_cast<const short*>(whbT);
    const short* bbase = wb + (size_t)(n0 + (lane & 15)) * 8 + (size_t)(lane >> 4) * 1024;

    for (int kc = 0; kc < KSL; kc += KC) {
        const int dbuf = (kc >> 7) & 1;
        #pragma unroll
        for (int v = 0; v < 4; ++v) {
            const int vid = v * 512 + tid;
            const int r = vid >> 5;                      // 32 threads per row
            const int c4 = (vid & 31) << 2;
            const int jl = kc + c4;                      // col within slice
            const int j = k0 + jl;                       // global col
            const int wbw = ((jl >> 8) << 3) + (((jl >> 7) & 1) << 2);
            i32x4 w4 = *(const i32x4*)(&bmL[r][wbw]);
            const unsigned p = (jl >> 2) & 31;
            const float c1 = crowL[r][0], c2 = crowL[r][1], a1i = crowL[r][2];
            f32x4 pa = *(const f32x4*)(pkf + 2 * j);
            f32x4 pb = *(const f32x4*)(pkf + 2 * j + 4);
            f32x4 al;
            {
                unsigned ub = __float_as_uint(pa.y);
                float e1 = __uint_as_float(ub << 16), e2 = __uint_as_float(ub & 0xffff0000u);
                al.x = ((w4.x >> p) & 1) ? ((a1i + pa.x >= 0.f) ? c1 * e1 : c2 * e2) : 0.f;
            }
            {
                unsigned ub = __float_as_uint(pa.w);
                float e1 = __uint_as_float(ub << 16), e2 = __uint_as_float(ub & 0xffff0000u);
                al.y = ((w4.y >> p) & 1) ? ((a1i + pa.z >= 0.f) ? c1 * e1 : c2 * e2) : 0.f;
            }
            {
                unsigned ub = __float_as_uint(pb.y);
                float e1 = __uint_as_float(ub << 16), e2 = __uint_as_float(ub & 0xffff0000u);
                al.z = ((w4.z >> p) & 1) ? ((a1i + pb.x >= 0.f) ? c1 * e1 : c2 * e2) : 0.f;
            }
            {
                unsigned ub = __float_as_uint(pb.w);
                float e1 = __uint_as_float(ub << 16), e2 = __uint_as_float(ub & 0xffff0000u);
                al.w = ((w4.w >> p) & 1) ? ((a1i + pb.z >= 0.f) ? c1 * e1 : c2 * e2) : 0.f;
            }
            __builtin_nontemporal_store(al, (f32x4*)(alpha + (size_t)(r0 + r) * NN + j));
            u16x4 ub4;
            ub4.x = f2bf(al.x); ub4.y = f2bf(al.y); ub4.z = f2bf(al.z); ub4.w = f2bf(al.w);
            *(u16x4*)(&abuf[dbuf][r][c4]) = ub4;
        }
        __syncthreads();
        #pragma unroll
        for (int kk = 0; kk < KC; kk += 32) {
            bf16x8 bf = *(const bf16x8*)(bbase + (size_t)((k0 + kc + kk) >> 3) * 1024);
            #pragma unroll
            for (int rt = 0; rt < 4; ++rt) {
                bf16x8 af = *(const bf16x8*)(&abuf[dbuf][rt * 16 + (lane & 15)][kk + 8 * (lane >> 4)]);
                acc[rt] = __builtin_amdgcn_mfma_f32_16x16x32_bf16(af, bf, acc[rt], 0, 0, 0);
            }
        }
    }

    float* pb2 = part + (size_t)ks * NN * DIM;
    const int rb = (lane >> 4) * 4;
    #pragma unroll
    for (int rt = 0; rt < 4; ++rt) {
        #pragma unroll
        for (int q = 0; q < 4; ++q)
            __builtin_nontemporal_store(acc[rt][q],
                pb2 + (size_t)(r0 + rt * 16 + rb + q) * DIM + n0 + (lane & 15));
    }
}

// ---------------------------------------------------------------------------
// K5: reduce split-K partials -> out (vectorized, NT reads)
// ---------------------------------------------------------------------------
__global__ __launch_bounds__(256) void k5_reduce(const float* __restrict__ part,
                                                 float* __restrict__ out) {
    const size_t idx = ((size_t)blockIdx.x * 256 + threadIdx.x) * 4;
    f32x4 s = (f32x4){0.f, 0.f, 0.f, 0.f};
    #pragma unroll
    for (int ks = 0; ks < KS; ++ks)
        s += __builtin_nontemporal_load((const f32x4*)(part + (size_t)ks * NN * DIM + idx));
    *(f32x4*)(out + idx) = s;
}

// ---------------------------------------------------------------------------
extern "C" void kernel_launch(void* const* d_in, const int* in_sizes, int n_in,
                              void* d_out, int out_size, void* d_ws, size_t ws_size,
                              hipStream_t stream) {
    const float* h   = (const float*)d_in[0];
    const int*   adj = (const int*)d_in[1];
    const float* W   = (const float*)d_in[2];
    const float* a   = (const float*)d_in[3];

    float* out   = (float*)d_out;
    float* alpha = out + (size_t)NN * DIM;

    char* ws = (char*)d_ws;
    __hip_bfloat16* whbT = (__hip_bfloat16*)(ws);          // 2 MB
    float* a1g   = (float*)(ws + 0x200000);                // 32 KB
    float2* pk   = (float2*)(ws + 0x208000);               // 64 KB
    float* crow  = (float*)(ws + 0x218000);                // 128 KB
    unsigned* bm = (unsigned*)(ws + 0x240000);             // 8 MB
    float* part  = (float*)(ws + 0xA40000);                // KS*4 MB = 32 MB

    k1m<<<NN / 64, 256, 0, stream>>>(h, W, a, whbT, a1g, pk);
    sa_scan<<<NN / 4, 256, 0, stream>>>(adj, a1g, pk, bm, crow);
    sb_pv<<<dim3(NN / RPB, KS), 512, 0, stream>>>(bm, crow, pk, whbT, alpha, part);
    k5_reduce<<<NN * DIM / 1024, 256, 0, stream>>>(part, out);
}